// Round 1
// baseline (1238.238 us; speedup 1.0000x reference)
//
#include <hip/hip_runtime.h>
#include <stdint.h>

// RetinaNet postprocess on MI355X.
// 336 blocks = 3 levels x 16 images x 7 fg classes; 256 threads/block.
// Per block: exact radix-select (sigmoid bits) -> gather -> bitonic sort
// (score desc, index asc) -> decode 500 boxes -> IoU bitmask -> greedy scan.

namespace {
constexpr int KSEL = 500;
constexpr int CAP  = 1024;
constexpr int BIMG = 16;
constexpr int NCLS = 7;           // fg classes (class 0 skipped)
constexpr int OFF_SCORES = 672000;   // 3*16*7*500*4
constexpr int OFF_KEEP   = 840000;
constexpr int OFF_LABELS = 1008000;
}

__device__ __forceinline__ float sigmoid_ref(float x) {
#pragma clang fp contract(off)
    return 1.0f / (1.0f + expf(-x));
}

__global__ __launch_bounds__(256) void retina_post_kernel(
    const float* __restrict__ cls0, const float* __restrict__ reg0,
    const float* __restrict__ cls1, const float* __restrict__ reg1,
    const float* __restrict__ cls2, const float* __restrict__ reg2,
    float* __restrict__ out)
{
    const int bx   = blockIdx.x;
    const int l    = bx / (BIMG * NCLS);
    const int rem  = bx % (BIMG * NCLS);
    const int bimg = rem / NCLS;
    const int c    = rem % NCLS;
    const int tid  = threadIdx.x;
    const int lane = tid & 63;
    const int wid  = tid >> 6;

    int H, W; float stride, asize;
    const float *cls, *reg;
    if (l == 0)      { H = 192; W = 192; stride = 8.0f;  asize = 16.0f; cls = cls0; reg = reg0; }
    else if (l == 1) { H = 96;  W = 96;  stride = 16.0f; asize = 32.0f; cls = cls1; reg = reg1; }
    else             { H = 48;  W = 48;  stride = 32.0f; asize = 64.0f; cls = cls2; reg = reg2; }
    const int HW = H * W;
    const int c1 = c + 1;

    __shared__ unsigned long long s_keys[CAP];       // 8 KB
    __shared__ float              s_box[KSEL * 4];   // 8 KB
    __shared__ float              s_area[KSEL];      // 2 KB
    __shared__ unsigned long long s_mask[KSEL * 8];  // 32 KB
    __shared__ unsigned long long s_alive[8];
    __shared__ unsigned           s_hist[4 * 16];
    __shared__ unsigned           s_prefix;
    __shared__ unsigned           s_cgt;
    __shared__ int                s_m;
    __shared__ int                s_need4;
    __shared__ int                s_gshift;

    // ---- init ----
    for (int i = tid; i < CAP; i += 256) s_keys[i] = 0ull;
    if (tid == 0) { s_prefix = 0u; s_cgt = 0u; s_m = 0; s_need4 = 0; s_gshift = 20; }

    // ---- radix-select on sigmoid bits: 3 passes of 4 bits (+ optional 4th) ----
    for (int pass = 0; pass < 4; ++pass) {
        if (pass == 3 && !s_need4) break;   // uniform (set before last barrier)
        if (tid < 64) s_hist[tid] = 0u;
        __syncthreads();
        const unsigned pref = s_prefix;
        const unsigned cgt  = s_cgt;
        const int shp = 32 - 4 * pass;
        const int shn = 28 - 4 * pass;
        unsigned cnt[16];
#pragma unroll
        for (int q = 0; q < 16; ++q) cnt[q] = 0u;
        for (int a = 0; a < 3; ++a) {
            const float* p = cls + (size_t)(bimg * 24 + a * 8 + c1) * (size_t)HW;
            for (int hw = tid; hw < HW; hw += 256) {
                float s = sigmoid_ref(p[hw]);
                unsigned bits = __float_as_uint(s);
                bool match = (pass == 0) || ((bits >> shp) == pref);
                unsigned sel = match ? ((bits >> shn) & 0xFu) : 0xFFu;
#pragma unroll
                for (int q = 0; q < 16; ++q) {
                    unsigned long long bal = __ballot((int)(sel == (unsigned)q));
                    cnt[q] += (unsigned)__popcll(bal);
                }
            }
        }
        if (lane == 0) {
#pragma unroll
            for (int q = 0; q < 16; ++q) s_hist[wid * 16 + q] = cnt[q];
        }
        __syncthreads();
        if (tid == 0) {
            unsigned tot[16];
#pragma unroll
            for (int q = 0; q < 16; ++q)
                tot[q] = s_hist[q] + s_hist[16 + q] + s_hist[32 + q] + s_hist[48 + q];
            unsigned acc = cgt;
            int t = 0;
            for (int q = 15; q >= 0; --q) {
                if (acc + tot[q] >= (unsigned)KSEL) { t = q; break; }
                acc += tot[q];
            }
            s_prefix = (pref << 4) | (unsigned)t;
            s_cgt = acc;
            if (pass == 2) s_need4 = (acc + tot[t] > (unsigned)CAP) ? 1 : 0;
            if (pass == 3) s_gshift = 16;
        }
        __syncthreads();
    }

    // ---- gather candidates (bits-prefix >= threshold prefix) ----
    {
        const unsigned gpref = s_prefix;
        const int gsh = s_gshift;
        for (int a = 0; a < 3; ++a) {
            const float* p = cls + (size_t)(bimg * 24 + a * 8 + c1) * (size_t)HW;
            for (int hw = tid; hw < HW; hw += 256) {
                float s = sigmoid_ref(p[hw]);
                unsigned bits = __float_as_uint(s);
                if ((bits >> gsh) >= gpref) {
                    int pos = atomicAdd(&s_m, 1);
                    if (pos < CAP) {
                        unsigned n = (unsigned)(hw * 3 + a);
                        s_keys[pos] = ((unsigned long long)bits << 32)
                                    | (unsigned long long)(0xFFFFFFFFu - n);
                    }
                }
            }
        }
    }

    // ---- bitonic sort CAP keys, descending (score desc, index asc) ----
    for (int k2 = 2; k2 <= CAP; k2 <<= 1) {
        for (int j = k2 >> 1; j >= 1; j >>= 1) {
            __syncthreads();
            for (int i = tid; i < CAP; i += 256) {
                int ixj = i ^ j;
                if (ixj > i) {
                    unsigned long long va = s_keys[i], vb = s_keys[ixj];
                    bool desc = ((i & k2) == 0);
                    if (desc ? (va < vb) : (va > vb)) {
                        s_keys[i] = vb; s_keys[ixj] = va;
                    }
                }
            }
        }
    }
    __syncthreads();

    // ---- decode selected boxes, write boxes/scores/labels, build valid mask ----
    const size_t probIdx  = (size_t)((l * BIMG + bimg) * NCLS + c);
    float* outBoxes  = out + probIdx * (size_t)(KSEL * 4);
    float* outScores = out + OFF_SCORES + probIdx * (size_t)KSEL;
    float* outKeep   = out + OFF_KEEP   + probIdx * (size_t)KSEL;
    float* outLabels = out + OFF_LABELS + probIdx * (size_t)KSEL;

    for (int it = 0; it < 2; ++it) {
        int r = it * 256 + tid;
        bool pred = false;
        if (r < KSEL) {
            unsigned long long key = s_keys[r];
            unsigned bits = (unsigned)(key >> 32);
            float sc = __uint_as_float(bits);
            unsigned n = 0xFFFFFFFFu - (unsigned)(key & 0xFFFFFFFFull);
            int a  = (int)(n % 3u);
            int hw = (int)(n / 3u);
            int h = hw / W, w = hw % W;
            float b0, b1, b2, b3;
            {
#pragma clang fp contract(off)
                float ar  = (a == 0) ? 0.5f : ((a == 1) ? 1.0f : 2.0f);
                float sq  = sqrtf(ar);
                float was = asize * sq;
                float has = asize / sq;
                float cx0 = ((float)w + 0.5f) * stride;
                float cy0 = ((float)h + 0.5f) * stride;
                float x1 = cx0 - 0.5f * was;
                float y1 = cy0 - 0.5f * has;
                float x2 = cx0 + 0.5f * was;
                float y2 = cy0 + 0.5f * has;
                float wa = x2 - x1;
                float ha = y2 - y1;
                float cxa = x1 + 0.5f * wa;
                float cya = y1 + 0.5f * ha;
                const float* rp = reg + (size_t)(bimg * 12 + a * 4) * (size_t)HW + (size_t)hw;
                float dx = rp[0];
                float dy = rp[(size_t)HW];
                float dw = rp[(size_t)2 * HW];
                float dh = rp[(size_t)3 * HW];
                float bcx = dx * wa + cxa;
                float bcy = dy * ha + cya;
                float bw  = expf(dw) * wa;
                float bh  = expf(dh) * ha;
                b0 = bcx - 0.5f * bw;
                b1 = bcy - 0.5f * bh;
                b2 = bcx + 0.5f * bw;
                b3 = bcy + 0.5f * bh;
                s_box[r * 4 + 0] = b0; s_box[r * 4 + 1] = b1;
                s_box[r * 4 + 2] = b2; s_box[r * 4 + 3] = b3;
                s_area[r] = (b2 - b0) * (b3 - b1);
            }
            outBoxes[r * 4 + 0] = b0; outBoxes[r * 4 + 1] = b1;
            outBoxes[r * 4 + 2] = b2; outBoxes[r * 4 + 3] = b3;
            outScores[r] = sc;
            outLabels[r] = (float)c;
            pred = sc > 0.05f;
        }
        unsigned long long bal = __ballot((int)pred);
        if (lane == 0) s_alive[it * 4 + wid] = bal;
    }
    __syncthreads();

    // ---- IoU suppression bitmask: row i has bits only for j > i ----
    for (int i = tid; i < KSEL; i += 256) {
        float x1i = s_box[i * 4 + 0], y1i = s_box[i * 4 + 1];
        float x2i = s_box[i * 4 + 2], y2i = s_box[i * 4 + 3];
        float ai = s_area[i];
        for (int ww = 0; ww < 8; ++ww) {
            unsigned long long m = 0ull;
            int jbase = ww * 64;
            int jend = jbase + 64; if (jend > KSEL) jend = KSEL;
            int j0 = jbase > (i + 1) ? jbase : (i + 1);
            for (int j = j0; j < jend; ++j) {
#pragma clang fp contract(off)
                float ix1 = fmaxf(x1i, s_box[j * 4 + 0]);
                float iy1 = fmaxf(y1i, s_box[j * 4 + 1]);
                float ix2 = fminf(x2i, s_box[j * 4 + 2]);
                float iy2 = fminf(y2i, s_box[j * 4 + 3]);
                float iw = fmaxf(ix2 - ix1, 0.0f);
                float ih = fmaxf(iy2 - iy1, 0.0f);
                float inter = iw * ih;
                float uni = ai + s_area[j] - inter;
                float iou = inter / fmaxf(uni, 1e-9f);
                if (iou > 0.5f) m |= (1ull << (j - jbase));
            }
            s_mask[i * 8 + ww] = m;
        }
    }
    __syncthreads();

    // ---- greedy scan, single wave, lanes 0..7 own 64-bit alive words ----
    if (tid < 64) {
        unsigned long long al = (lane < 8) ? s_alive[lane] : 0ull;
        for (int i = 0; i < KSEL; ++i) {
            unsigned long long aw = __shfl(al, i >> 6);
            if ((aw >> (i & 63)) & 1ull) {
                if (lane < 8) al &= ~s_mask[i * 8 + lane];
            }
        }
        if (lane < 8) s_alive[lane] = al;
    }
    __syncthreads();

    // ---- write keep ----
    for (int it = 0; it < 2; ++it) {
        int r = it * 256 + tid;
        if (r < KSEL) {
            unsigned long long w64 = s_alive[r >> 6];
            outKeep[r] = ((w64 >> (r & 63)) & 1ull) ? 1.0f : 0.0f;
        }
    }
}

extern "C" void kernel_launch(void* const* d_in, const int* in_sizes, int n_in,
                              void* d_out, int out_size, void* d_ws, size_t ws_size,
                              hipStream_t stream) {
    (void)d_ws; (void)ws_size; (void)out_size;
    const float *cls0 = nullptr, *reg0 = nullptr, *cls1 = nullptr,
                *reg1 = nullptr, *cls2 = nullptr, *reg2 = nullptr;
    for (int i = 0; i < n_in; ++i) {
        switch (in_sizes[i]) {
            case 14155776: cls0 = (const float*)d_in[i]; break;  // 16*24*192*192
            case 7077888:  reg0 = (const float*)d_in[i]; break;  // 16*12*192*192
            case 3538944:  cls1 = (const float*)d_in[i]; break;  // 16*24*96*96
            case 1769472:  reg1 = (const float*)d_in[i]; break;  // 16*12*96*96
            case 884736:   cls2 = (const float*)d_in[i]; break;  // 16*24*48*48
            case 442368:   reg2 = (const float*)d_in[i]; break;  // 16*12*48*48
            default: break;
        }
    }
    retina_post_kernel<<<dim3(336), dim3(256), 0, stream>>>(
        cls0, reg0, cls1, reg1, cls2, reg2, (float*)d_out);
}

// Round 2
// 510.404 us; speedup vs baseline: 2.4260x; 2.4260x over previous
//
#include <hip/hip_runtime.h>
#include <stdint.h>

// RetinaNet postprocess on MI355X — multi-kernel pipeline.
// k_zero -> k_hist (per-problem 2048-bin sigmoid-bits histogram, 1232 blocks)
//        -> k_gather (threshold from histogram suffix, gather candidates)
//        -> k_final (sort 1024, decode, IoU, greedy NMS, write) per problem.

namespace {
constexpr int KSEL = 500;
constexpr int CAP  = 1024;
constexpr int BIMG = 16;
constexpr int NCLS = 7;             // fg classes (class 0 skipped)
constexpr int NPROB = 336;          // 3*16*7
constexpr int NBINS = 2048;
constexpr int OFF_SCORES = 672000;  // 3*16*7*500*4
constexpr int OFF_KEEP   = 840000;
constexpr int OFF_LABELS = 1008000;

// workspace layout (words/bytes)
constexpr int HIST_WORDS   = NPROB * NBINS;           // 688128 u32
constexpr int CNT_WORD_OFF = HIST_WORDS;              // 336 u32
constexpr int ZERO_WORDS   = HIST_WORDS + NPROB;      // 688464
constexpr size_t CAND_BYTE_OFF = (size_t)ZERO_WORDS * 4; // 2753856, 8-aligned
constexpr size_t WS_NEED = CAND_BYTE_OFF + (size_t)NPROB * CAP * 8; // ~5.5 MB

constexpr int NB_SCAN = 1232;  // 112*8 + 112*2 + 112*1
}

__device__ __forceinline__ float sigmoid_ref(float x) {
#pragma clang fp contract(off)
    return 1.0f / (1.0f + expf(-x));
}

// decode scan-block index -> (level, img, class, hw-range)
__device__ __forceinline__ void scan_decode(int bx, int& l, int& img, int& c,
                                            int& p, int& HW, int& hw0, int& hw1) {
    int pidL, chunk, chunkHW;
    if (bx < 896)        { l = 0; pidL = bx >> 3;        chunk = bx & 7; chunkHW = 4608; HW = 36864; }
    else if (bx < 1120)  { l = 1; pidL = (bx - 896) >> 1; chunk = (bx - 896) & 1; chunkHW = 4608; HW = 9216; }
    else                 { l = 2; pidL = bx - 1120;       chunk = 0;      chunkHW = 2304; HW = 2304; }
    img = pidL / NCLS; c = pidL % NCLS;
    p = (l * BIMG + img) * NCLS + c;
    hw0 = chunk * chunkHW; hw1 = hw0 + chunkHW;
}

__global__ __launch_bounds__(256) void k_zero(unsigned* __restrict__ w, int nwords) {
    int i = blockIdx.x * 256 + threadIdx.x;
    if (i < nwords) w[i] = 0u;
}

__global__ __launch_bounds__(256) void k_hist(
    const float* __restrict__ cls0, const float* __restrict__ cls1,
    const float* __restrict__ cls2, unsigned* __restrict__ g_hist)
{
    const int tid = threadIdx.x;
    int l, img, c, p, HW, hw0, hw1;
    scan_decode(blockIdx.x, l, img, c, p, HW, hw0, hw1);
    const float* cls = (l == 0) ? cls0 : (l == 1) ? cls1 : cls2;

    __shared__ unsigned h[NBINS];
    for (int i = tid; i < NBINS; i += 256) h[i] = 0u;
    __syncthreads();
    for (int a = 0; a < 3; ++a) {
        const float* pb = cls + (size_t)(img * 24 + a * 8 + c + 1) * (size_t)HW;
        for (int hw = hw0 + tid; hw < hw1; hw += 256) {
            unsigned bits = __float_as_uint(sigmoid_ref(pb[hw]));
            atomicAdd(&h[bits >> 19], 1u);
        }
    }
    __syncthreads();
    unsigned* gh = g_hist + (size_t)p * NBINS;
    for (int i = tid; i < NBINS; i += 256) {
        unsigned v = h[i];
        if (v) atomicAdd(&gh[i], v);
    }
}

__global__ __launch_bounds__(256) void k_gather(
    const float* __restrict__ cls0, const float* __restrict__ cls1,
    const float* __restrict__ cls2, const unsigned* __restrict__ g_hist,
    unsigned* __restrict__ g_cnt, unsigned long long* __restrict__ g_cand)
{
    const int tid = threadIdx.x;
    int l, img, c, p, HW, hw0, hw1;
    scan_decode(blockIdx.x, l, img, c, p, HW, hw0, hw1);
    const float* cls = (l == 0) ? cls0 : (l == 1) ? cls1 : cls2;

    __shared__ unsigned h8s[256];
    __shared__ unsigned s_t;
    const unsigned* gh = g_hist + (size_t)p * NBINS;
    unsigned sum8 = 0;
#pragma unroll
    for (int j = 0; j < 8; ++j) sum8 += gh[tid * 8 + j];
    h8s[tid] = sum8;
    __syncthreads();
    unsigned S = 0;
    for (int j = 255; j >= tid; --j) S += h8s[j];   // suffix sum incl. own chunk
    unsigned Snext = S - sum8;
    if (S >= (unsigned)KSEL && Snext < (unsigned)KSEL) {
        unsigned acc = Snext;
        int t = tid * 8;
        for (int b = tid * 8 + 7; b >= tid * 8; --b) {
            acc += gh[b];
            if (acc >= (unsigned)KSEL) { t = b; break; }
        }
        s_t = (unsigned)t;
    }
    __syncthreads();
    const unsigned t = s_t;

    unsigned long long* cand = g_cand + (size_t)p * CAP;
    for (int a = 0; a < 3; ++a) {
        const float* pb = cls + (size_t)(img * 24 + a * 8 + c + 1) * (size_t)HW;
        for (int hw = hw0 + tid; hw < hw1; hw += 256) {
            unsigned bits = __float_as_uint(sigmoid_ref(pb[hw]));
            if ((bits >> 19) >= t) {
                unsigned pos = atomicAdd(&g_cnt[p], 1u);
                if (pos < (unsigned)CAP) {
                    unsigned n = (unsigned)(hw * 3 + a);
                    cand[pos] = ((unsigned long long)bits << 32)
                              | (unsigned long long)(0xFFFFFFFFu - n);
                }
            }
        }
    }
}

__global__ __launch_bounds__(256) void k_final(
    const float* __restrict__ reg0, const float* __restrict__ reg1,
    const float* __restrict__ reg2, const unsigned* __restrict__ g_cnt,
    const unsigned long long* __restrict__ g_cand, float* __restrict__ out)
{
    const int p    = blockIdx.x;
    const int l    = p / (BIMG * NCLS);
    const int rem  = p % (BIMG * NCLS);
    const int bimg = rem / NCLS;
    const int c    = rem % NCLS;
    const int tid  = threadIdx.x;
    const int lane = tid & 63;
    const int wid  = tid >> 6;

    int W, HW; float stride, asize;
    const float* reg;
    if (l == 0)      { W = 192; HW = 36864; stride = 8.0f;  asize = 16.0f; reg = reg0; }
    else if (l == 1) { W = 96;  HW = 9216;  stride = 16.0f; asize = 32.0f; reg = reg1; }
    else             { W = 48;  HW = 2304;  stride = 32.0f; asize = 64.0f; reg = reg2; }

    __shared__ unsigned long long s_keys[CAP];       // 8 KB
    __shared__ float              s_box[KSEL * 4];   // 8 KB
    __shared__ float              s_area[KSEL];      // 2 KB
    __shared__ unsigned long long s_mask[KSEL * 8];  // 32 KB
    __shared__ unsigned long long s_alive[8];

    unsigned cnt = g_cnt[p];
    if (cnt > (unsigned)CAP) cnt = CAP;
    const unsigned long long* cand = g_cand + (size_t)p * CAP;
    for (int i = tid; i < CAP; i += 256)
        s_keys[i] = (i < (int)cnt) ? cand[i] : 0ull;

    // bitonic sort CAP keys descending (score desc, index asc)
    for (int k2 = 2; k2 <= CAP; k2 <<= 1) {
        for (int j = k2 >> 1; j >= 1; j >>= 1) {
            __syncthreads();
            for (int i = tid; i < CAP; i += 256) {
                int ixj = i ^ j;
                if (ixj > i) {
                    unsigned long long va = s_keys[i], vb = s_keys[ixj];
                    bool desc = ((i & k2) == 0);
                    if (desc ? (va < vb) : (va > vb)) {
                        s_keys[i] = vb; s_keys[ixj] = va;
                    }
                }
            }
        }
    }
    __syncthreads();

    const size_t probIdx = (size_t)p;
    float* outBoxes  = out + probIdx * (size_t)(KSEL * 4);
    float* outScores = out + OFF_SCORES + probIdx * (size_t)KSEL;
    float* outKeep   = out + OFF_KEEP   + probIdx * (size_t)KSEL;
    float* outLabels = out + OFF_LABELS + probIdx * (size_t)KSEL;

    for (int it = 0; it < 2; ++it) {
        int r = it * 256 + tid;
        bool pred = false;
        if (r < KSEL) {
            unsigned long long key = s_keys[r];
            unsigned bits = (unsigned)(key >> 32);
            float sc = __uint_as_float(bits);
            unsigned n = 0xFFFFFFFFu - (unsigned)(key & 0xFFFFFFFFull);
            int a  = (int)(n % 3u);
            int hw = (int)(n / 3u);
            int h = hw / W, w = hw % W;
            float b0, b1, b2, b3;
            {
#pragma clang fp contract(off)
                float ar  = (a == 0) ? 0.5f : ((a == 1) ? 1.0f : 2.0f);
                float sq  = sqrtf(ar);
                float was = asize * sq;
                float has = asize / sq;
                float cx0 = ((float)w + 0.5f) * stride;
                float cy0 = ((float)h + 0.5f) * stride;
                float x1 = cx0 - 0.5f * was;
                float y1 = cy0 - 0.5f * has;
                float x2 = cx0 + 0.5f * was;
                float y2 = cy0 + 0.5f * has;
                float wa = x2 - x1;
                float ha = y2 - y1;
                float cxa = x1 + 0.5f * wa;
                float cya = y1 + 0.5f * ha;
                const float* rp = reg + (size_t)(bimg * 12 + a * 4) * (size_t)HW + (size_t)hw;
                float dx = rp[0];
                float dy = rp[(size_t)HW];
                float dw = rp[(size_t)2 * HW];
                float dh = rp[(size_t)3 * HW];
                float bcx = dx * wa + cxa;
                float bcy = dy * ha + cya;
                float bw  = expf(dw) * wa;
                float bh  = expf(dh) * ha;
                b0 = bcx - 0.5f * bw;
                b1 = bcy - 0.5f * bh;
                b2 = bcx + 0.5f * bw;
                b3 = bcy + 0.5f * bh;
                s_box[r * 4 + 0] = b0; s_box[r * 4 + 1] = b1;
                s_box[r * 4 + 2] = b2; s_box[r * 4 + 3] = b3;
                s_area[r] = (b2 - b0) * (b3 - b1);
            }
            outBoxes[r * 4 + 0] = b0; outBoxes[r * 4 + 1] = b1;
            outBoxes[r * 4 + 2] = b2; outBoxes[r * 4 + 3] = b3;
            outScores[r] = sc;
            outLabels[r] = (float)c;
            pred = sc > 0.05f;
        }
        unsigned long long bal = __ballot((int)pred);
        if (lane == 0) s_alive[it * 4 + wid] = bal;
    }
    __syncthreads();

    // IoU suppression bitmask: row i has bits only for j > i
    for (int i = tid; i < KSEL; i += 256) {
        float x1i = s_box[i * 4 + 0], y1i = s_box[i * 4 + 1];
        float x2i = s_box[i * 4 + 2], y2i = s_box[i * 4 + 3];
        float ai = s_area[i];
        for (int ww = 0; ww < 8; ++ww) {
            unsigned long long m = 0ull;
            int jbase = ww * 64;
            int jend = jbase + 64; if (jend > KSEL) jend = KSEL;
            int j0 = jbase > (i + 1) ? jbase : (i + 1);
            for (int j = j0; j < jend; ++j) {
#pragma clang fp contract(off)
                float ix1 = fmaxf(x1i, s_box[j * 4 + 0]);
                float iy1 = fmaxf(y1i, s_box[j * 4 + 1]);
                float ix2 = fminf(x2i, s_box[j * 4 + 2]);
                float iy2 = fminf(y2i, s_box[j * 4 + 3]);
                float iw = fmaxf(ix2 - ix1, 0.0f);
                float ih = fmaxf(iy2 - iy1, 0.0f);
                float inter = iw * ih;
                float uni = ai + s_area[j] - inter;
                float iou = inter / fmaxf(uni, 1e-9f);
                if (iou > 0.5f) m |= (1ull << (j - jbase));
            }
            s_mask[i * 8 + ww] = m;
        }
    }
    __syncthreads();

    // greedy scan, single wave
    if (tid < 64) {
        unsigned long long al = (lane < 8) ? s_alive[lane] : 0ull;
        for (int i = 0; i < KSEL; ++i) {
            unsigned long long aw = __shfl(al, i >> 6);
            if ((aw >> (i & 63)) & 1ull) {
                if (lane < 8) al &= ~s_mask[i * 8 + lane];
            }
        }
        if (lane < 8) s_alive[lane] = al;
    }
    __syncthreads();

    for (int it = 0; it < 2; ++it) {
        int r = it * 256 + tid;
        if (r < KSEL) {
            unsigned long long w64 = s_alive[r >> 6];
            outKeep[r] = ((w64 >> (r & 63)) & 1ull) ? 1.0f : 0.0f;
        }
    }
}

// ---------------- fallback: validated round-1 monolithic kernel ----------------
__global__ __launch_bounds__(256) void retina_post_kernel(
    const float* __restrict__ cls0, const float* __restrict__ reg0,
    const float* __restrict__ cls1, const float* __restrict__ reg1,
    const float* __restrict__ cls2, const float* __restrict__ reg2,
    float* __restrict__ out)
{
    const int bx   = blockIdx.x;
    const int l    = bx / (BIMG * NCLS);
    const int rem  = bx % (BIMG * NCLS);
    const int bimg = rem / NCLS;
    const int c    = rem % NCLS;
    const int tid  = threadIdx.x;
    const int lane = tid & 63;
    const int wid  = tid >> 6;

    int H, W; float stride, asize;
    const float *cls, *reg;
    if (l == 0)      { H = 192; W = 192; stride = 8.0f;  asize = 16.0f; cls = cls0; reg = reg0; }
    else if (l == 1) { H = 96;  W = 96;  stride = 16.0f; asize = 32.0f; cls = cls1; reg = reg1; }
    else             { H = 48;  W = 48;  stride = 32.0f; asize = 64.0f; cls = cls2; reg = reg2; }
    const int HW = H * W;
    const int c1 = c + 1;

    __shared__ unsigned long long s_keys[CAP];
    __shared__ float              s_box[KSEL * 4];
    __shared__ float              s_area[KSEL];
    __shared__ unsigned long long s_mask[KSEL * 8];
    __shared__ unsigned long long s_alive[8];
    __shared__ unsigned           s_hist[4 * 16];
    __shared__ unsigned           s_prefix;
    __shared__ unsigned           s_cgt;
    __shared__ int                s_m;
    __shared__ int                s_need4;
    __shared__ int                s_gshift;

    for (int i = tid; i < CAP; i += 256) s_keys[i] = 0ull;
    if (tid == 0) { s_prefix = 0u; s_cgt = 0u; s_m = 0; s_need4 = 0; s_gshift = 20; }

    for (int pass = 0; pass < 4; ++pass) {
        if (pass == 3 && !s_need4) break;
        if (tid < 64) s_hist[tid] = 0u;
        __syncthreads();
        const unsigned pref = s_prefix;
        const unsigned cgt  = s_cgt;
        const int shp = 32 - 4 * pass;
        const int shn = 28 - 4 * pass;
        unsigned cnt[16];
#pragma unroll
        for (int q = 0; q < 16; ++q) cnt[q] = 0u;
        for (int a = 0; a < 3; ++a) {
            const float* p = cls + (size_t)(bimg * 24 + a * 8 + c1) * (size_t)HW;
            for (int hw = tid; hw < HW; hw += 256) {
                float s = sigmoid_ref(p[hw]);
                unsigned bits = __float_as_uint(s);
                bool match = (pass == 0) || ((bits >> shp) == pref);
                unsigned sel = match ? ((bits >> shn) & 0xFu) : 0xFFu;
#pragma unroll
                for (int q = 0; q < 16; ++q) {
                    unsigned long long bal = __ballot((int)(sel == (unsigned)q));
                    cnt[q] += (unsigned)__popcll(bal);
                }
            }
        }
        if (lane == 0) {
#pragma unroll
            for (int q = 0; q < 16; ++q) s_hist[wid * 16 + q] = cnt[q];
        }
        __syncthreads();
        if (tid == 0) {
            unsigned tot[16];
#pragma unroll
            for (int q = 0; q < 16; ++q)
                tot[q] = s_hist[q] + s_hist[16 + q] + s_hist[32 + q] + s_hist[48 + q];
            unsigned acc = cgt;
            int t = 0;
            for (int q = 15; q >= 0; --q) {
                if (acc + tot[q] >= (unsigned)KSEL) { t = q; break; }
                acc += tot[q];
            }
            s_prefix = (pref << 4) | (unsigned)t;
            s_cgt = acc;
            if (pass == 2) s_need4 = (acc + tot[t] > (unsigned)CAP) ? 1 : 0;
            if (pass == 3) s_gshift = 16;
        }
        __syncthreads();
    }

    {
        const unsigned gpref = s_prefix;
        const int gsh = s_gshift;
        for (int a = 0; a < 3; ++a) {
            const float* p = cls + (size_t)(bimg * 24 + a * 8 + c1) * (size_t)HW;
            for (int hw = tid; hw < HW; hw += 256) {
                float s = sigmoid_ref(p[hw]);
                unsigned bits = __float_as_uint(s);
                if ((bits >> gsh) >= gpref) {
                    int pos = atomicAdd(&s_m, 1);
                    if (pos < CAP) {
                        unsigned n = (unsigned)(hw * 3 + a);
                        s_keys[pos] = ((unsigned long long)bits << 32)
                                    | (unsigned long long)(0xFFFFFFFFu - n);
                    }
                }
            }
        }
    }

    for (int k2 = 2; k2 <= CAP; k2 <<= 1) {
        for (int j = k2 >> 1; j >= 1; j >>= 1) {
            __syncthreads();
            for (int i = tid; i < CAP; i += 256) {
                int ixj = i ^ j;
                if (ixj > i) {
                    unsigned long long va = s_keys[i], vb = s_keys[ixj];
                    bool desc = ((i & k2) == 0);
                    if (desc ? (va < vb) : (va > vb)) {
                        s_keys[i] = vb; s_keys[ixj] = va;
                    }
                }
            }
        }
    }
    __syncthreads();

    const size_t probIdx  = (size_t)((l * BIMG + bimg) * NCLS + c);
    float* outBoxes  = out + probIdx * (size_t)(KSEL * 4);
    float* outScores = out + OFF_SCORES + probIdx * (size_t)KSEL;
    float* outKeep   = out + OFF_KEEP   + probIdx * (size_t)KSEL;
    float* outLabels = out + OFF_LABELS + probIdx * (size_t)KSEL;

    for (int it = 0; it < 2; ++it) {
        int r = it * 256 + tid;
        bool pred = false;
        if (r < KSEL) {
            unsigned long long key = s_keys[r];
            unsigned bits = (unsigned)(key >> 32);
            float sc = __uint_as_float(bits);
            unsigned n = 0xFFFFFFFFu - (unsigned)(key & 0xFFFFFFFFull);
            int a  = (int)(n % 3u);
            int hw = (int)(n / 3u);
            int h = hw / W, w = hw % W;
            float b0, b1, b2, b3;
            {
#pragma clang fp contract(off)
                float ar  = (a == 0) ? 0.5f : ((a == 1) ? 1.0f : 2.0f);
                float sq  = sqrtf(ar);
                float was = asize * sq;
                float has = asize / sq;
                float cx0 = ((float)w + 0.5f) * stride;
                float cy0 = ((float)h + 0.5f) * stride;
                float x1 = cx0 - 0.5f * was;
                float y1 = cy0 - 0.5f * has;
                float x2 = cx0 + 0.5f * was;
                float y2 = cy0 + 0.5f * has;
                float wa = x2 - x1;
                float ha = y2 - y1;
                float cxa = x1 + 0.5f * wa;
                float cya = y1 + 0.5f * ha;
                const float* rp = reg + (size_t)(bimg * 12 + a * 4) * (size_t)HW + (size_t)hw;
                float dx = rp[0];
                float dy = rp[(size_t)HW];
                float dw = rp[(size_t)2 * HW];
                float dh = rp[(size_t)3 * HW];
                float bcx = dx * wa + cxa;
                float bcy = dy * ha + cya;
                float bw  = expf(dw) * wa;
                float bh  = expf(dh) * ha;
                b0 = bcx - 0.5f * bw;
                b1 = bcy - 0.5f * bh;
                b2 = bcx + 0.5f * bw;
                b3 = bcy + 0.5f * bh;
                s_box[r * 4 + 0] = b0; s_box[r * 4 + 1] = b1;
                s_box[r * 4 + 2] = b2; s_box[r * 4 + 3] = b3;
                s_area[r] = (b2 - b0) * (b3 - b1);
            }
            outBoxes[r * 4 + 0] = b0; outBoxes[r * 4 + 1] = b1;
            outBoxes[r * 4 + 2] = b2; outBoxes[r * 4 + 3] = b3;
            outScores[r] = sc;
            outLabels[r] = (float)c;
            pred = sc > 0.05f;
        }
        unsigned long long bal = __ballot((int)pred);
        if (lane == 0) s_alive[it * 4 + wid] = bal;
    }
    __syncthreads();

    for (int i = tid; i < KSEL; i += 256) {
        float x1i = s_box[i * 4 + 0], y1i = s_box[i * 4 + 1];
        float x2i = s_box[i * 4 + 2], y2i = s_box[i * 4 + 3];
        float ai = s_area[i];
        for (int ww = 0; ww < 8; ++ww) {
            unsigned long long m = 0ull;
            int jbase = ww * 64;
            int jend = jbase + 64; if (jend > KSEL) jend = KSEL;
            int j0 = jbase > (i + 1) ? jbase : (i + 1);
            for (int j = j0; j < jend; ++j) {
#pragma clang fp contract(off)
                float ix1 = fmaxf(x1i, s_box[j * 4 + 0]);
                float iy1 = fmaxf(y1i, s_box[j * 4 + 1]);
                float ix2 = fminf(x2i, s_box[j * 4 + 2]);
                float iy2 = fminf(y2i, s_box[j * 4 + 3]);
                float iw = fmaxf(ix2 - ix1, 0.0f);
                float ih = fmaxf(iy2 - iy1, 0.0f);
                float inter = iw * ih;
                float uni = ai + s_area[j] - inter;
                float iou = inter / fmaxf(uni, 1e-9f);
                if (iou > 0.5f) m |= (1ull << (j - jbase));
            }
            s_mask[i * 8 + ww] = m;
        }
    }
    __syncthreads();

    if (tid < 64) {
        unsigned long long al = (lane < 8) ? s_alive[lane] : 0ull;
        for (int i = 0; i < KSEL; ++i) {
            unsigned long long aw = __shfl(al, i >> 6);
            if ((aw >> (i & 63)) & 1ull) {
                if (lane < 8) al &= ~s_mask[i * 8 + lane];
            }
        }
        if (lane < 8) s_alive[lane] = al;
    }
    __syncthreads();

    for (int it = 0; it < 2; ++it) {
        int r = it * 256 + tid;
        if (r < KSEL) {
            unsigned long long w64 = s_alive[r >> 6];
            outKeep[r] = ((w64 >> (r & 63)) & 1ull) ? 1.0f : 0.0f;
        }
    }
}

extern "C" void kernel_launch(void* const* d_in, const int* in_sizes, int n_in,
                              void* d_out, int out_size, void* d_ws, size_t ws_size,
                              hipStream_t stream) {
    (void)out_size;
    const float *cls0 = nullptr, *reg0 = nullptr, *cls1 = nullptr,
                *reg1 = nullptr, *cls2 = nullptr, *reg2 = nullptr;
    for (int i = 0; i < n_in; ++i) {
        switch (in_sizes[i]) {
            case 14155776: cls0 = (const float*)d_in[i]; break;  // 16*24*192*192
            case 7077888:  reg0 = (const float*)d_in[i]; break;  // 16*12*192*192
            case 3538944:  cls1 = (const float*)d_in[i]; break;  // 16*24*96*96
            case 1769472:  reg1 = (const float*)d_in[i]; break;  // 16*12*96*96
            case 884736:   cls2 = (const float*)d_in[i]; break;  // 16*24*48*48
            case 442368:   reg2 = (const float*)d_in[i]; break;  // 16*12*48*48
            default: break;
        }
    }
    float* out = (float*)d_out;

    if (ws_size < WS_NEED) {
        // fallback: validated monolithic kernel
        retina_post_kernel<<<dim3(NPROB), dim3(256), 0, stream>>>(
            cls0, reg0, cls1, reg1, cls2, reg2, out);
        return;
    }

    unsigned* g_hist = (unsigned*)d_ws;
    unsigned* g_cnt  = (unsigned*)d_ws + CNT_WORD_OFF;
    unsigned long long* g_cand =
        (unsigned long long*)((char*)d_ws + CAND_BYTE_OFF);

    k_zero<<<dim3((ZERO_WORDS + 255) / 256), dim3(256), 0, stream>>>(
        (unsigned*)d_ws, ZERO_WORDS);
    k_hist<<<dim3(NB_SCAN), dim3(256), 0, stream>>>(cls0, cls1, cls2, g_hist);
    k_gather<<<dim3(NB_SCAN), dim3(256), 0, stream>>>(cls0, cls1, cls2,
                                                      g_hist, g_cnt, g_cand);
    k_final<<<dim3(NPROB), dim3(256), 0, stream>>>(reg0, reg1, reg2,
                                                   g_cnt, g_cand, out);
}